// Round 2
// baseline (150.862 us; speedup 1.0000x reference)
//
#include <hip/hip_runtime.h>

// Problem constants (from reference):
//   B=256, A=128, D=5, FA=256, FB=64, C=256, F = FA+FB = 320
// deg==5 (~96.2% of rows) -> output row exactly zero. Only deg<5 rows
// (~1250, of which ~98% have deg==4) need feat(320) @ W[deg](320x256).
//
// Lesson from last round: touching d_ws triggers a 256MiB workspace
// re-poison fill (~41us) per iteration -> NEVER use the workspace.
//
// Single fused kernel, 512 blocks x 64 rows:
//   phase 1: float4-zero the block's 64 output rows (coalesced, write-BW)
//   phase 2: degree scan -> per-deg needy lists in LDS (no global scratch)
//   phase 3: same-deg chunks of 8 rows; feat transposed in LDS so each
//            W[deg][f][c] global load feeds 8 FMAs (8x less W L2 traffic
//            than the one-row-per-block baseline)

#define NB 256
#define NA 128
#define ND 5
#define NFA 256
#define NFB 64
#define NC 256
#define NF (NFA + NFB)     // 320
#define NROWS (NB * NA)    // 32768
#define RPB 64             // rows per block
#define RPC 8              // rows per compute chunk (same deg)
#define NBLK (NROWS / RPB) // 512 blocks -> 2 per CU, all co-resident

__global__ __launch_bounds__(256) void ngh_fused_kernel(
    const float* __restrict__ atoms,   // B*A*FA
    const float* __restrict__ bonds,   // B*A*D*FB (row slice = 320 contiguous)
    const int*   __restrict__ edges,   // B*A*D
    const float* __restrict__ W,       // D*F*C
    const float* __restrict__ bias,    // D*C
    float* __restrict__ out)           // B*A*C
{
    __shared__ float feat[NF * RPC];      // 10 KB, layout [f][r], stride 8
    __shared__ int   cnt_s[ND];
    __shared__ int   lists[ND][RPB];      // per-deg needy row lists
    const int t  = threadIdx.x;
    const int r0 = blockIdx.x * RPB;

    if (t < ND) cnt_s[t] = 0;

    // ---- phase 1: zero 64 rows = 4096 float4, 16 per thread, coalesced ----
    float4* dst = reinterpret_cast<float4*>(out + (size_t)r0 * NC);
    const float4 z = make_float4(0.f, 0.f, 0.f, 0.f);
#pragma unroll
    for (int k = 0; k < (RPB * NC / 4) / 256; ++k) dst[t + k * 256] = z;

    __syncthreads();   // cnt_s init visible before atomics

    // ---- phase 2: degree scan, LDS compaction (one row per thread) ----
    if (t < RPB) {
        const int row = r0 + t;
        const int* er = edges + row * ND;
        int deg = 0;
#pragma unroll
        for (int d = 0; d < ND; ++d) deg += (er[d] != -1) ? 1 : 0;
        if (deg < ND) {
            const int p = atomicAdd(&cnt_s[deg], 1);
            lists[deg][p] = row;
        }
    }
    __syncthreads();   // lists ready; also orders phase-1 stores (vmcnt drain)
                       // before phase-3 overwrites of needy rows

    // ---- phase 3: per-deg chunks of up to 8 rows ----
    for (int d = 0; d < ND; ++d) {
        const int n = cnt_s[d];                 // block-uniform
        for (int j0 = 0; j0 < n; j0 += RPC) {
            const int nr = min(RPC, n - j0);
            int rows_r[RPC];                    // statically indexed (no scratch)
#pragma unroll
            for (int r = 0; r < RPC; ++r)
                rows_r[r] = (r < nr) ? lists[d][j0 + r] : -1;

            // Build feat[f][r]. thread t = atom channel f; t<64 also bonds.
            // All branches block-uniform (rows_r identical across threads).
#pragma unroll
            for (int r = 0; r < RPC; ++r) {
                const int row = rows_r[r];
                float v = 0.f;
                if (row >= 0) {
                    const int rb = row & ~(NA - 1);   // b*NA
                    const int* er = edges + row * ND;
                    v = atoms[(size_t)row * NFA + t];
#pragma unroll
                    for (int dd = 0; dd < ND; ++dd) {
                        const int e = er[dd];
                        if (e != -1) v += atoms[(size_t)(rb + e) * NFA + t];
                    }
                }
                feat[t * RPC + r] = v;
                if (t < NFB) {
                    float bs = 0.f;
                    if (row >= 0) {
                        const float* br = bonds + (size_t)row * (ND * NFB) + t;
#pragma unroll
                        for (int dd = 0; dd < ND; ++dd) bs += br[dd * NFB];
                    }
                    feat[(NFA + t) * RPC + r] = bs;
                }
            }
            __syncthreads();

            // Matvec: out[c=t] for 8 rows. W load coalesced (256B/wave),
            // each loaded w feeds 8 FMAs. feat reads are same-address
            // broadcast ds_read_b128 (16B-aligned, stride 8) -> conflict-free.
            const float* Wd = W + (size_t)d * (NF * NC) + t;
            const float bv = bias[d * NC + t];
            float acc[RPC];
#pragma unroll
            for (int r = 0; r < RPC; ++r) acc[r] = bv;
#pragma unroll 4
            for (int f = 0; f < NF; ++f) {
                const float w = Wd[(size_t)f * NC];
                const float4 p0 = *reinterpret_cast<const float4*>(&feat[f * RPC]);
                const float4 p1 = *reinterpret_cast<const float4*>(&feat[f * RPC + 4]);
                acc[0] = fmaf(p0.x, w, acc[0]);
                acc[1] = fmaf(p0.y, w, acc[1]);
                acc[2] = fmaf(p0.z, w, acc[2]);
                acc[3] = fmaf(p0.w, w, acc[3]);
                acc[4] = fmaf(p1.x, w, acc[4]);
                acc[5] = fmaf(p1.y, w, acc[5]);
                acc[6] = fmaf(p1.z, w, acc[6]);
                acc[7] = fmaf(p1.w, w, acc[7]);
            }
#pragma unroll
            for (int r = 0; r < RPC; ++r)
                if (rows_r[r] >= 0)
                    out[(size_t)rows_r[r] * NC + t] = fmaxf(acc[r], 0.f);
            __syncthreads();   // before next chunk overwrites feat
        }
    }
}

// ---------------------------------------------------------------------------
extern "C" void kernel_launch(void* const* d_in, const int* in_sizes, int n_in,
                              void* d_out, int out_size, void* d_ws, size_t ws_size,
                              hipStream_t stream) {
    const float* atoms = (const float*)d_in[0];
    const float* bonds = (const float*)d_in[1];
    const int*   edges = (const int*)  d_in[2];
    const float* W     = (const float*)d_in[3];
    const float* bias  = (const float*)d_in[4];
    float*       out   = (float*)d_out;

    // NOTE: d_ws deliberately untouched (workspace use costs a 256MiB
    // re-poison fill per iteration in this harness).
    ngh_fused_kernel<<<dim3(NBLK), dim3(256), 0, stream>>>(
        atoms, bonds, edges, W, bias, out);
}

// Round 5
// 136.729 us; speedup vs baseline: 1.1034x; 1.1034x over previous
//
#include <hip/hip_runtime.h>

// Problem constants (from reference):
//   B=256, A=128, D=5, FA=256, FB=64, C=256, F = FA+FB = 320
// deg==5 (~96.2% of rows) -> output row exactly zero. Only deg<5 rows
// (~1250, ~98% deg==4) need feat(320) @ W[deg](320x256).
//
// Lessons so far:
//   R1: touching d_ws triggers a 256MiB re-poison fill (~41us/iter) -> never
//       use the workspace. Fixed floor = 2 poison fills ~83us + our kernel.
//   R2: concentrating needy work (512 blocks, 8-row chunks) killed
//       parallelism (69us > 43.7us baseline). Distribution > reuse here.
//   R3/R4: container failed twice (likely infra). Resubmitting same design,
//       hardened: barriers never behind any branch; deg bitmask (no
//       runtime-indexed register array); trivial stores hoisted to a
//       barrier-free prologue.
//
// Structure: 4096 blocks x 8 rows, 256 threads.
//   - block's 40 edge ints staged via one coalesced load into LDS
//   - deg for all 8 rows -> bitmask (block-uniform)
//   - prologue: all trivial rows zero-stored, no barriers, stores overlap
//   - needy rows (~0.3/block): feat in LDS; matvec f-split across 4 waves
//     (80 f each), lane owns 4 channels via float4 W loads -> 80 wide loads
//     per wave vs 320 scalar; LDS reduce; float4 coalesced store.

#define NB 256
#define NA 128
#define ND 5
#define NFA 256
#define NFB 64
#define NC 256
#define NF (NFA + NFB)     // 320
#define NROWS (NB * NA)    // 32768
#define RPB 8              // rows per block
#define NBLK (NROWS / RPB) // 4096 blocks -> 16/CU, ~8 co-resident

__global__ __launch_bounds__(256) void ngh_kernel(
    const float* __restrict__ atoms,   // B*A*FA
    const float* __restrict__ bonds,   // B*A*D*FB (row slice = 320 contiguous)
    const int*   __restrict__ edges,   // B*A*D
    const float* __restrict__ W,       // D*F*C
    const float* __restrict__ bias,    // D*C
    float* __restrict__ out)           // B*A*C
{
    __shared__ alignas(16) float  feat[NF];      // 1.25 KB
    __shared__ alignas(16) float4 red[4][NC / 4];// 4 KB (per-wave partials)
    __shared__ int                eds[RPB * ND]; // 160 B

    const int t  = threadIdx.x;
    const int r0 = blockIdx.x * RPB;
    const int w  = t >> 6;             // wave id 0..3
    const int l  = t & 63;             // lane id

    // Stage this block's 40 edge ints with one coalesced load.
    if (t < RPB * ND) eds[t] = edges[r0 * ND + t];
    __syncthreads();

    // Degree scan for all rows -> bitmask (block-uniform: same LDS reads).
    unsigned needy = 0;
#pragma unroll
    for (int r = 0; r < RPB; ++r) {
        int dg = 0;
#pragma unroll
        for (int d = 0; d < ND; ++d) dg += (eds[r * ND + d] != -1) ? 1 : 0;
        needy |= (dg < ND) ? (1u << r) : 0u;
    }

    // Prologue: zero-store every trivial row; no barriers, stores overlap.
#pragma unroll
    for (int r = 0; r < RPB; ++r)
        if (!((needy >> r) & 1u))
            out[(size_t)(r0 + r) * NC + t] = 0.0f;

    if (needy == 0u) return;           // ~73% of blocks exit here

    // Needy rows: every __syncthreads() below is executed by ALL threads
    // of the block (loop bounds static, branch condition block-uniform,
    // barriers outside any divergent region).
    for (int r = 0; r < RPB; ++r) {
        if (!((needy >> r) & 1u)) continue;   // block-uniform
        const int row = r0 + r;

        int e[ND];
        int deg = 0;
#pragma unroll
        for (int d = 0; d < ND; ++d) {
            e[d] = eds[r * ND + d];
            deg += (e[d] != -1) ? 1 : 0;
        }

        // ---- feat = [summed_atom(256) | summed_bond(64)] in LDS ----
        {
            const int rb = row & ~(NA - 1);          // b*NA
            float v = atoms[(size_t)row * NFA + t];
#pragma unroll
            for (int d = 0; d < ND; ++d)
                if (e[d] != -1) v += atoms[(size_t)(rb + e[d]) * NFA + t];
            feat[t] = v;
            if (t < NFB) {
                const float* br = bonds + (size_t)row * (ND * NFB) + t;
                feat[NFA + t] = br[0] + br[NFB] + br[2 * NFB]
                              + br[3 * NFB] + br[4 * NFB];
            }
        }
        __syncthreads();               // feat ready

        // ---- matvec: wave w owns f in [80w, 80w+80); lane owns 4 channels.
        // W loads: float4/lane, 64 lanes cover the 256-chan row (1KB/instr),
        // 80 load instrs per wave (vs 320 scalar) -> 4x fewer round-trips.
        const float* Wd = W + (size_t)deg * (NF * NC);
        float4 acc = make_float4(0.f, 0.f, 0.f, 0.f);
        const int fbase = w * (NF / 4);
#pragma unroll 2
        for (int fi = 0; fi < NF / 4; fi += 4) {
            const int f = fbase + fi;
            const float4 fv = *reinterpret_cast<const float4*>(&feat[f]);
            const float4 w0 = *reinterpret_cast<const float4*>(&Wd[(size_t)(f + 0) * NC + l * 4]);
            const float4 w1 = *reinterpret_cast<const float4*>(&Wd[(size_t)(f + 1) * NC + l * 4]);
            const float4 w2 = *reinterpret_cast<const float4*>(&Wd[(size_t)(f + 2) * NC + l * 4]);
            const float4 w3 = *reinterpret_cast<const float4*>(&Wd[(size_t)(f + 3) * NC + l * 4]);
            acc.x = fmaf(fv.x, w0.x, acc.x);
            acc.y = fmaf(fv.x, w0.y, acc.y);
            acc.z = fmaf(fv.x, w0.z, acc.z);
            acc.w = fmaf(fv.x, w0.w, acc.w);
            acc.x = fmaf(fv.y, w1.x, acc.x);
            acc.y = fmaf(fv.y, w1.y, acc.y);
            acc.z = fmaf(fv.y, w1.z, acc.z);
            acc.w = fmaf(fv.y, w1.w, acc.w);
            acc.x = fmaf(fv.z, w2.x, acc.x);
            acc.y = fmaf(fv.z, w2.y, acc.y);
            acc.z = fmaf(fv.z, w2.z, acc.z);
            acc.w = fmaf(fv.z, w2.w, acc.w);
            acc.x = fmaf(fv.w, w3.x, acc.x);
            acc.y = fmaf(fv.w, w3.y, acc.y);
            acc.z = fmaf(fv.w, w3.z, acc.z);
            acc.w = fmaf(fv.w, w3.w, acc.w);
        }
        red[w][l] = acc;               // 16B/lane contiguous -> conflict-free
        __syncthreads();               // partials ready

        if (t < NC / 4) {              // wave 0 reduces + stores
            const float4 s0 = red[0][t];
            const float4 s1 = red[1][t];
            const float4 s2 = red[2][t];
            const float4 s3 = red[3][t];
            const float4 bv = *reinterpret_cast<const float4*>(&bias[deg * NC + t * 4]);
            float4 o;
            o.x = fmaxf(s0.x + s1.x + s2.x + s3.x + bv.x, 0.f);
            o.y = fmaxf(s0.y + s1.y + s2.y + s3.y + bv.y, 0.f);
            o.z = fmaxf(s0.z + s1.z + s2.z + s3.z + bv.z, 0.f);
            o.w = fmaxf(s0.w + s1.w + s2.w + s3.w + bv.w, 0.f);
            *reinterpret_cast<float4*>(&out[(size_t)row * NC + t * 4]) = o;
        }
        __syncthreads();               // feat/red reusable for next row
    }
}

// ---------------------------------------------------------------------------
extern "C" void kernel_launch(void* const* d_in, const int* in_sizes, int n_in,
                              void* d_out, int out_size, void* d_ws, size_t ws_size,
                              hipStream_t stream) {
    const float* atoms = (const float*)d_in[0];
    const float* bonds = (const float*)d_in[1];
    const int*   edges = (const int*)  d_in[2];
    const float* W     = (const float*)d_in[3];
    const float* bias  = (const float*)d_in[4];
    float*       out   = (float*)d_out;

    // d_ws deliberately untouched (workspace use costs a 256MiB re-poison
    // fill per iteration in this harness).
    ngh_kernel<<<dim3(NBLK), dim3(256), 0, stream>>>(
        atoms, bonds, edges, W, bias, out);
}